// Round 4
// baseline (316.135 us; speedup 1.0000x reference)
//
#include <hip/hip_runtime.h>
#include <hip/hip_bf16.h>

#define D_MODEL 1024
#define NUM_HEADS 16
#define HEAD_DIM 64
#define BATCH 4
#define SEQ 2048
#define MROWS (BATCH * SEQ)

using f32x4  = __attribute__((ext_vector_type(4))) float;
using bf16x8 = __attribute__((ext_vector_type(8))) short;

__device__ inline unsigned short f2bf(float f) {
    __hip_bfloat16 h = __float2bfloat16(f);
    return *reinterpret_cast<unsigned short*>(&h);
}

// async global->LDS, 16B per lane; lds base must be wave-uniform
__device__ inline void gld_lds16(const unsigned short* g, unsigned short* l) {
    __builtin_amdgcn_global_load_lds(
        (const __attribute__((address_space(1))) unsigned int*)g,
        (__attribute__((address_space(3))) unsigned int*)l, 16, 0, 0);
}

#define QSCALE 0.18033688011112042f   // 0.125 / ln(2)

// ---------------------------------------------------------------------------
// Build circulant weight matrices, B^T layout: Wt[n][k] = c[(n-k)&1023], bf16.
// Wq/bq (rows 0..1023) pre-scaled by QSCALE so attn can use exp2 directly.
// ---------------------------------------------------------------------------
__global__ __launch_bounds__(256) void build_w(
    const float* __restrict__ cq, const float* __restrict__ ck,
    const float* __restrict__ cv, const float* __restrict__ co,
    const float* __restrict__ bq, const float* __restrict__ bk,
    const float* __restrict__ bv, const float* __restrict__ bo,
    unsigned short* __restrict__ Wt, float* __restrict__ bias)
{
    const int n = blockIdx.x;
    const int sel = n >> 10, nl = n & 1023;
    const float* c  = sel == 0 ? cq : sel == 1 ? ck : sel == 2 ? cv : co;
    const float* bb = sel == 0 ? bq : sel == 1 ? bk : sel == 2 ? bv : bo;
    const float sc = (sel == 0) ? QSCALE : 1.0f;
    const int t = threadIdx.x;
    ushort4 o;
    o.x = f2bf(sc * c[(nl - (4*t + 0)) & 1023]);
    o.y = f2bf(sc * c[(nl - (4*t + 1)) & 1023]);
    o.z = f2bf(sc * c[(nl - (4*t + 2)) & 1023]);
    o.w = f2bf(sc * c[(nl - (4*t + 3)) & 1023]);
    ((ushort4*)(Wt + (size_t)n * 1024))[t] = o;
    if (t == 0) bias[n] = sc * bb[nl];
}

__global__ __launch_bounds__(256) void xcast(
    const float* __restrict__ x, unsigned short* __restrict__ xb)
{
    const size_t i = (size_t)blockIdx.x * 1024 + threadIdx.x * 4;
    float4 v = *(const float4*)(x + i);
    ushort4 o;
    o.x = f2bf(v.x); o.y = f2bf(v.y); o.z = f2bf(v.z); o.w = f2bf(v.w);
    *(ushort4*)(xb + i) = o;
}

// ---------------------------------------------------------------------------
// bf16 GEMM: C = A * W + bias. 128x128 tile, BK=64, XOR swizzle, gld_lds16.
// OUT_MODE 0: Q (pre-scaled weights) row-major; K row-major; V transposed
//             per (b,head).  OUT_MODE 1: fp32 out.  (Proven m97 structure.)
// ---------------------------------------------------------------------------
template <int OUT_MODE>
__global__ __launch_bounds__(256, 3) void gemm_circ(
    const unsigned short* __restrict__ A,
    const unsigned short* __restrict__ Bt,
    const float* __restrict__ bias,
    unsigned short* __restrict__ Qb, unsigned short* __restrict__ Kb,
    unsigned short* __restrict__ Vt, float* __restrict__ Cf)
{
    __shared__ unsigned short As[128 * 64];
    __shared__ unsigned short Bs[128 * 64];
    const int t = threadIdx.x;
    const int w = t >> 6, lane = t & 63;
    const int quad = lane >> 4, l16 = lane & 15;
    const int m0 = blockIdx.x * 128;
    const int n0 = blockIdx.y * 128;
    const int wm = (w & 1) * 64, wn = (w >> 1) * 64;

    f32x4 acc[4][4];
#pragma unroll
    for (int i = 0; i < 4; ++i)
#pragma unroll
        for (int j = 0; j < 4; ++j) acc[i][j] = (f32x4){0.f, 0.f, 0.f, 0.f};

    for (int k0 = 0; k0 < 1024; k0 += 64) {
        __syncthreads();
#pragma unroll
        for (int j = 0; j < 4; ++j) {
            const int s = j * 4 + w;
            const int i = s * 64 + lane;
            const int r = i >> 3;
            const int c = (i & 7) ^ (r & 7);
            gld_lds16(A  + (size_t)(m0 + r) * 1024 + k0 + c * 8, &As[s * 512]);
            gld_lds16(Bt + (size_t)(n0 + r) * 1024 + k0 + c * 8, &Bs[s * 512]);
        }
        __syncthreads();

#pragma unroll
        for (int kk = 0; kk < 2; ++kk) {
            bf16x8 af[4], bfr[4];
#pragma unroll
            for (int i = 0; i < 4; ++i) {
                const int r = wm + i * 16 + l16;
                const int slot = r * 8 + ((kk * 4 + quad) ^ (r & 7));
                af[i] = *(const bf16x8*)&As[slot * 8];
            }
#pragma unroll
            for (int j = 0; j < 4; ++j) {
                const int r = wn + j * 16 + l16;
                const int slot = r * 8 + ((kk * 4 + quad) ^ (r & 7));
                bfr[j] = *(const bf16x8*)&Bs[slot * 8];
            }
#pragma unroll
            for (int i = 0; i < 4; ++i)
#pragma unroll
                for (int j = 0; j < 4; ++j)
                    acc[i][j] = __builtin_amdgcn_mfma_f32_16x16x32_bf16(
                        af[i], bfr[j], acc[i][j], 0, 0, 0);
        }
    }

#pragma unroll
    for (int i = 0; i < 4; ++i) {
        const int gm = m0 + wm + i * 16 + quad * 4;
#pragma unroll
        for (int j = 0; j < 4; ++j) {
            const int gn = n0 + wn + j * 16 + l16;
            const float bv = bias[gn];
            if (OUT_MODE == 1) {
#pragma unroll
                for (int rr = 0; rr < 4; ++rr)
                    Cf[(size_t)(gm + rr) * 1024 + gn] = acc[i][j][rr] + bv;
            } else {
                const int sel = gn >> 10;
                if (sel == 0) {
#pragma unroll
                    for (int rr = 0; rr < 4; ++rr)
                        Qb[(size_t)(gm + rr) * 1024 + gn] = f2bf(acc[i][j][rr] + bv);
                } else if (sel == 1) {
                    const int col = gn & 1023;
#pragma unroll
                    for (int rr = 0; rr < 4; ++rr)
                        Kb[(size_t)(gm + rr) * 1024 + col] = f2bf(acc[i][j][rr] + bv);
                } else {
                    const int d = gn & 1023;
                    const int head = d >> 6, dl = d & 63;
                    const int b = gm >> 11, key = gm & 2047;
                    ushort4 vv;
                    vv.x = f2bf(acc[i][j][0] + bv);
                    vv.y = f2bf(acc[i][j][1] + bv);
                    vv.z = f2bf(acc[i][j][2] + bv);
                    vv.w = f2bf(acc[i][j][3] + bv);
                    *(ushort4*)&Vt[((size_t)((b * 16 + head) * 64 + dl)) * 2048 + key] = vv;
                }
            }
        }
    }
}

// ---------------------------------------------------------------------------
// MFMA attention v10: NO LDS. K/V per (b,head) = 512KB, L2-resident (8 heads
// per XCD = 4MB with bh-fast grid), and both Kb [key][d] and Vt [d][key] are
// 16B-chunk-aligned exactly as the MFMA fragments need -> load kf/vf directly
// from global (L2 hits), drop staging, double-buffer, and ALL barriers.
// Back to s=4 strips (64 q/wave, 1:4 read:MFMA amortization). ILP latency
// cover: vf issued before the QK^T that precedes its PV use; next kf
// prefetched one full iteration ahead (rotated kfA/kfB, no reg copies).
// Math bit-identical to v8/v9 (same key permutation, same accum order).
// ---------------------------------------------------------------------------
__global__ __launch_bounds__(256, 2) void attn_mfma(
    const unsigned short* __restrict__ Qb, const unsigned short* __restrict__ Kb,
    const unsigned short* __restrict__ Vt, unsigned short* __restrict__ O)
{
    const int t = threadIdx.x;
    const int w = t >> 6, lane = t & 63;
    const int quad = lane >> 4, l16 = lane & 15;
    const int bh = blockIdx.x;                  // fast axis: (b,head)
    const int b = bh >> 4, head = bh & 15;
    const int qbase = blockIdx.y * 256 + w * 64;

    // Q fragments (B-operand of S^T = K Q^T): lane l16 = q-col, regs = d.
    bf16x8 qa[4][2];
#pragma unroll
    for (int s = 0; s < 4; ++s)
#pragma unroll
        for (int h = 0; h < 2; ++h) {
            size_t off = (size_t)(b * SEQ + qbase + s*16 + l16) * D_MODEL
                       + head * HEAD_DIM + h*32 + quad*8;
            qa[s][h] = *(const bf16x8*)(Qb + off);
        }

    f32x4 acc[4][4];   // [strip][d-tile], C-layout row=q, col=d
#pragma unroll
    for (int s = 0; s < 4; ++s)
#pragma unroll
        for (int dt = 0; dt < 4; ++dt) acc[s][dt] = (f32x4){0.f,0.f,0.f,0.f};
    float lp[4] = {0.f, 0.f, 0.f, 0.f};  // per-lane partial row sum, q = s*16+l16

    const unsigned short* Kh = Kb + (size_t)(b * SEQ) * D_MODEL + head * HEAD_DIM;
    const unsigned short* Vh = Vt + (size_t)((b * NUM_HEADS + head) * HEAD_DIM) * SEQ;

    // A-row permutation: row a holds key kh*32 + (a>>2)*8 + m*4 + (a&3)
    const int krow = ((l16 >> 2) << 3) + (l16 & 3);
    const int dq = quad * 8;                    // 16B d-chunk within a K row

    bf16x8 kfA[2][2][2], kfB[2][2][2];          // [kh][m][h]

    // preload kf for key-block 0
#pragma unroll
    for (int kh = 0; kh < 2; ++kh)
#pragma unroll
        for (int m = 0; m < 2; ++m)
#pragma unroll
            for (int h = 0; h < 2; ++h)
                kfA[kh][m][h] = *(const bf16x8*)(
                    Kh + (size_t)(kh*32 + krow + m*4) * D_MODEL + h*32 + dq);

    auto body = [&](int kb, bf16x8 (&kfc)[2][2][2], bf16x8 (&kfn)[2][2][2]) {
        // prefetch kf for NEXT key-block (covered by this block's compute)
        if (kb + 64 < SEQ) {
#pragma unroll
            for (int kh = 0; kh < 2; ++kh)
#pragma unroll
                for (int m = 0; m < 2; ++m)
#pragma unroll
                    for (int h = 0; h < 2; ++h)
                        kfn[kh][m][h] = *(const bf16x8*)(
                            Kh + (size_t)(kb + 64 + kh*32 + krow + m*4) * D_MODEL
                               + h*32 + dq);
        }

#pragma unroll
        for (int kh = 0; kh < 2; ++kh) {
            // V fragments for this 32-key half, issued before QK^T (L2 cover)
            bf16x8 vfr[4];
#pragma unroll
            for (int dt = 0; dt < 4; ++dt)
                vfr[dt] = *(const bf16x8*)(
                    Vh + (size_t)(dt*16 + l16) * SEQ + kb + kh*32 + dq);

            // S^T = K Q^T with interleaved key rows; exp2; pack -> in-reg pf
            bf16x8 pf[4];
#pragma unroll
            for (int s = 0; s < 4; ++s) {
                f32x4 st0 = (f32x4){0.f,0.f,0.f,0.f};
                f32x4 st1 = (f32x4){0.f,0.f,0.f,0.f};
#pragma unroll
                for (int h = 0; h < 2; ++h) {
                    st0 = __builtin_amdgcn_mfma_f32_16x16x32_bf16(
                        kfc[kh][0][h], qa[s][h], st0, 0, 0, 0);
                    st1 = __builtin_amdgcn_mfma_f32_16x16x32_bf16(
                        kfc[kh][1][h], qa[s][h], st1, 0, 0, 0);
                }
                // lane holds keys kh*32 + quad*8 + {0..7} for q = s*16+l16
                float p0 = __builtin_amdgcn_exp2f(st0[0]);
                float p1 = __builtin_amdgcn_exp2f(st0[1]);
                float p2 = __builtin_amdgcn_exp2f(st0[2]);
                float p3 = __builtin_amdgcn_exp2f(st0[3]);
                float p4 = __builtin_amdgcn_exp2f(st1[0]);
                float p5 = __builtin_amdgcn_exp2f(st1[1]);
                float p6 = __builtin_amdgcn_exp2f(st1[2]);
                float p7 = __builtin_amdgcn_exp2f(st1[3]);
                lp[s] += ((p0 + p1) + (p2 + p3)) + ((p4 + p5) + (p6 + p7));
                __hip_bfloat162 w0 = __float22bfloat162_rn(make_float2(p0, p1));
                __hip_bfloat162 w1 = __float22bfloat162_rn(make_float2(p2, p3));
                __hip_bfloat162 w2 = __float22bfloat162_rn(make_float2(p4, p5));
                __hip_bfloat162 w3 = __float22bfloat162_rn(make_float2(p6, p7));
                union { bf16x8 v; unsigned int u[4]; } pu;
                pu.u[0] = *reinterpret_cast<unsigned int*>(&w0);
                pu.u[1] = *reinterpret_cast<unsigned int*>(&w1);
                pu.u[2] = *reinterpret_cast<unsigned int*>(&w2);
                pu.u[3] = *reinterpret_cast<unsigned int*>(&w3);
                pf[s] = pu.v;
            }

            // O += P V for this 32-key half (pf in-register, vf from L2)
#pragma unroll
            for (int dt = 0; dt < 4; ++dt)
#pragma unroll
                for (int s = 0; s < 4; ++s)
                    acc[s][dt] = __builtin_amdgcn_mfma_f32_16x16x32_bf16(
                        pf[s], vfr[dt], acc[s][dt], 0, 0, 0);
        }
    };

    for (int kb = 0; kb < SEQ; kb += 128) {
        body(kb,      kfA, kfB);
        body(kb + 64, kfB, kfA);
    }

    // complete row sums: lanes {l16, +16, +32, +48} hold disjoint k-partials
#pragma unroll
    for (int s = 0; s < 4; ++s) {
        lp[s] += __shfl_xor(lp[s], 16);
        lp[s] += __shfl_xor(lp[s], 32);
    }

#pragma unroll
    for (int s = 0; s < 4; ++s)
#pragma unroll
        for (int rr = 0; rr < 4; ++rr) {
            // denom for q = s*16 + quad*4 + rr lives at lane (quad*4+rr)
            float denom = __shfl(lp[s], quad * 4 + rr);
            float inv = 1.0f / denom;
            int q = qbase + s*16 + quad*4 + rr;
            unsigned short* orow = O + (size_t)(b * SEQ + q) * D_MODEL + head * HEAD_DIM + l16;
#pragma unroll
            for (int dt = 0; dt < 4; ++dt) orow[dt*16] = f2bf(acc[s][dt][rr] * inv);
        }
}

extern "C" void kernel_launch(void* const* d_in, const int* in_sizes, int n_in,
                              void* d_out, int out_size, void* d_ws, size_t ws_size,
                              hipStream_t stream) {
    const float* x    = (const float*)d_in[0];
    const float* wq_c = (const float*)d_in[1];
    const float* wq_b = (const float*)d_in[2];
    const float* wk_c = (const float*)d_in[3];
    const float* wk_b = (const float*)d_in[4];
    const float* wv_c = (const float*)d_in[5];
    const float* wv_b = (const float*)d_in[6];
    const float* wo_c = (const float*)d_in[7];
    const float* wo_b = (const float*)d_in[8];
    float* out = (float*)d_out;

    char* ws = (char*)d_ws;
    unsigned short* Wt   = (unsigned short*)(ws);                        // 8 MB
    float*          bias = (float*)(ws + ((size_t)8  << 20));            // 16 KB
    unsigned short* xb   = (unsigned short*)(ws + ((size_t)10 << 20));   // 16 MB
    unsigned short* Qb   = (unsigned short*)(ws + ((size_t)26 << 20));   // 16 MB
    unsigned short* Kb   = (unsigned short*)(ws + ((size_t)42 << 20));   // 16 MB
    unsigned short* Vt   = (unsigned short*)(ws + ((size_t)58 << 20));   // 16 MB
    unsigned short* Ob   = (unsigned short*)(ws + ((size_t)74 << 20));   // 16 MB

    build_w<<<4096, 256, 0, stream>>>(wq_c, wk_c, wv_c, wo_c,
                                      wq_b, wk_b, wv_b, wo_b, Wt, bias);
    xcast<<<MROWS, 256, 0, stream>>>(x, xb);
    gemm_circ<0><<<dim3(64, 24), 256, 0, stream>>>(xb, Wt, bias, Qb, Kb, Vt, nullptr);
    // fast axis = (b,head): round-robin over XCDs; q-tiles (slow) revisit warm L2
    attn_mfma<<<dim3(BATCH * NUM_HEADS, SEQ / 256), 256, 0, stream>>>(Qb, Kb, Vt, Ob);
    gemm_circ<1><<<dim3(64, 8), 256, 0, stream>>>(Ob, Wt + (size_t)3072 * 1024,
                                                  bias + 3072, nullptr, nullptr, nullptr, out);
}

// Round 5
// 246.378 us; speedup vs baseline: 1.2831x; 1.2831x over previous
//
#include <hip/hip_runtime.h>
#include <hip/hip_bf16.h>

#define D_MODEL 1024
#define NUM_HEADS 16
#define HEAD_DIM 64
#define BATCH 4
#define SEQ 2048
#define MROWS (BATCH * SEQ)

using f32x4  = __attribute__((ext_vector_type(4))) float;
using bf16x8 = __attribute__((ext_vector_type(8))) short;

__device__ inline unsigned short f2bf(float f) {
    __hip_bfloat16 h = __float2bfloat16(f);
    return *reinterpret_cast<unsigned short*>(&h);
}

// async global->LDS, 16B per lane; lds base must be wave-uniform
__device__ inline void gld_lds16(const unsigned short* g, unsigned short* l) {
    __builtin_amdgcn_global_load_lds(
        (const __attribute__((address_space(1))) unsigned int*)g,
        (__attribute__((address_space(3))) unsigned int*)l, 16, 0, 0);
}

#define QSCALE 0.18033688011112042f   // 0.125 / ln(2)

// ---------------------------------------------------------------------------
// Build circulant weight matrices, B^T layout: Wt[n][k] = c[(n-k)&1023], bf16.
// Wq/bq (rows 0..1023) pre-scaled by QSCALE so attn can use exp2 directly.
// ---------------------------------------------------------------------------
__global__ __launch_bounds__(256) void build_w(
    const float* __restrict__ cq, const float* __restrict__ ck,
    const float* __restrict__ cv, const float* __restrict__ co,
    const float* __restrict__ bq, const float* __restrict__ bk,
    const float* __restrict__ bv, const float* __restrict__ bo,
    unsigned short* __restrict__ Wt, float* __restrict__ bias)
{
    const int n = blockIdx.x;
    const int sel = n >> 10, nl = n & 1023;
    const float* c  = sel == 0 ? cq : sel == 1 ? ck : sel == 2 ? cv : co;
    const float* bb = sel == 0 ? bq : sel == 1 ? bk : sel == 2 ? bv : bo;
    const float sc = (sel == 0) ? QSCALE : 1.0f;
    const int t = threadIdx.x;
    ushort4 o;
    o.x = f2bf(sc * c[(nl - (4*t + 0)) & 1023]);
    o.y = f2bf(sc * c[(nl - (4*t + 1)) & 1023]);
    o.z = f2bf(sc * c[(nl - (4*t + 2)) & 1023]);
    o.w = f2bf(sc * c[(nl - (4*t + 3)) & 1023]);
    ((ushort4*)(Wt + (size_t)n * 1024))[t] = o;
    if (t == 0) bias[n] = sc * bb[nl];
}

__global__ __launch_bounds__(256) void xcast(
    const float* __restrict__ x, unsigned short* __restrict__ xb)
{
    const size_t i = (size_t)blockIdx.x * 1024 + threadIdx.x * 4;
    float4 v = *(const float4*)(x + i);
    ushort4 o;
    o.x = f2bf(v.x); o.y = f2bf(v.y); o.z = f2bf(v.z); o.w = f2bf(v.w);
    *(ushort4*)(xb + i) = o;
}

// ---------------------------------------------------------------------------
// bf16 GEMM: C = A * W + bias. 128x128 tile, BK=64, XOR swizzle, gld_lds16.
// OUT_MODE 0: Q (pre-scaled weights) row-major; K row-major; V transposed
//             per (b,head).  OUT_MODE 1: fp32 out.  (Proven m97 structure.)
// ---------------------------------------------------------------------------
template <int OUT_MODE>
__global__ __launch_bounds__(256, 3) void gemm_circ(
    const unsigned short* __restrict__ A,
    const unsigned short* __restrict__ Bt,
    const float* __restrict__ bias,
    unsigned short* __restrict__ Qb, unsigned short* __restrict__ Kb,
    unsigned short* __restrict__ Vt, float* __restrict__ Cf)
{
    __shared__ unsigned short As[128 * 64];
    __shared__ unsigned short Bs[128 * 64];
    const int t = threadIdx.x;
    const int w = t >> 6, lane = t & 63;
    const int quad = lane >> 4, l16 = lane & 15;
    const int m0 = blockIdx.x * 128;
    const int n0 = blockIdx.y * 128;
    const int wm = (w & 1) * 64, wn = (w >> 1) * 64;

    f32x4 acc[4][4];
#pragma unroll
    for (int i = 0; i < 4; ++i)
#pragma unroll
        for (int j = 0; j < 4; ++j) acc[i][j] = (f32x4){0.f, 0.f, 0.f, 0.f};

    for (int k0 = 0; k0 < 1024; k0 += 64) {
        __syncthreads();
#pragma unroll
        for (int j = 0; j < 4; ++j) {
            const int s = j * 4 + w;
            const int i = s * 64 + lane;
            const int r = i >> 3;
            const int c = (i & 7) ^ (r & 7);
            gld_lds16(A  + (size_t)(m0 + r) * 1024 + k0 + c * 8, &As[s * 512]);
            gld_lds16(Bt + (size_t)(n0 + r) * 1024 + k0 + c * 8, &Bs[s * 512]);
        }
        __syncthreads();

#pragma unroll
        for (int kk = 0; kk < 2; ++kk) {
            bf16x8 af[4], bfr[4];
#pragma unroll
            for (int i = 0; i < 4; ++i) {
                const int r = wm + i * 16 + l16;
                const int slot = r * 8 + ((kk * 4 + quad) ^ (r & 7));
                af[i] = *(const bf16x8*)&As[slot * 8];
            }
#pragma unroll
            for (int j = 0; j < 4; ++j) {
                const int r = wn + j * 16 + l16;
                const int slot = r * 8 + ((kk * 4 + quad) ^ (r & 7));
                bfr[j] = *(const bf16x8*)&Bs[slot * 8];
            }
#pragma unroll
            for (int i = 0; i < 4; ++i)
#pragma unroll
                for (int j = 0; j < 4; ++j)
                    acc[i][j] = __builtin_amdgcn_mfma_f32_16x16x32_bf16(
                        af[i], bfr[j], acc[i][j], 0, 0, 0);
        }
    }

#pragma unroll
    for (int i = 0; i < 4; ++i) {
        const int gm = m0 + wm + i * 16 + quad * 4;
#pragma unroll
        for (int j = 0; j < 4; ++j) {
            const int gn = n0 + wn + j * 16 + l16;
            const float bv = bias[gn];
            if (OUT_MODE == 1) {
#pragma unroll
                for (int rr = 0; rr < 4; ++rr)
                    Cf[(size_t)(gm + rr) * 1024 + gn] = acc[i][j][rr] + bv;
            } else {
                const int sel = gn >> 10;
                if (sel == 0) {
#pragma unroll
                    for (int rr = 0; rr < 4; ++rr)
                        Qb[(size_t)(gm + rr) * 1024 + gn] = f2bf(acc[i][j][rr] + bv);
                } else if (sel == 1) {
                    const int col = gn & 1023;
#pragma unroll
                    for (int rr = 0; rr < 4; ++rr)
                        Kb[(size_t)(gm + rr) * 1024 + col] = f2bf(acc[i][j][rr] + bv);
                } else {
                    const int d = gn & 1023;
                    const int head = d >> 6, dl = d & 63;
                    const int b = gm >> 11, key = gm & 2047;
                    ushort4 vv;
                    vv.x = f2bf(acc[i][j][0] + bv);
                    vv.y = f2bf(acc[i][j][1] + bv);
                    vv.z = f2bf(acc[i][j][2] + bv);
                    vv.w = f2bf(acc[i][j][3] + bv);
                    *(ushort4*)&Vt[((size_t)((b * 16 + head) * 64 + dl)) * 2048 + key] = vv;
                }
            }
        }
    }
}

// ---------------------------------------------------------------------------
// MFMA attention v11 = v9 (proven 87us: in-register P, key-interleave,
// 4 blocks/CU) + MFMA row-sum: softmax denominator computed by one extra
// MFMA per (s,kh) against an all-ones B-operand instead of 28 VALU adds/iter.
// C-layout bonus: denom(q = s*16+quad*4+rr) lands in acc_sum[s][rr] of EVERY
// lane -> the epilogue shuffle chains are deleted too. Denominator now sums
// bf16-rounded P, consistent with the PV numerator (also bf16 P).
// ---------------------------------------------------------------------------
__global__ __launch_bounds__(256, 4) void attn_mfma(
    const unsigned short* __restrict__ Qb, const unsigned short* __restrict__ Kb,
    const unsigned short* __restrict__ Vt, unsigned short* __restrict__ O)
{
    __shared__ unsigned short Ks[2][64 * 64];   // [buf][key][d] swizzled (sg)
    __shared__ unsigned short Vs[2][64 * 64];   // [buf][d][key] swizzled (r&7)

    const int t = threadIdx.x;
    const int w = t >> 6, lane = t & 63;
    const int quad = lane >> 4, l16 = lane & 15;
    const int bh = blockIdx.x;                  // fast axis: (b,head)
    const int b = bh >> 4, head = bh & 15;
    const int qbase = blockIdx.y * 128 + w * 32;

    // Q fragments (B-operand of S^T = K Q^T): lane l16 = q-col, regs = d.
    bf16x8 qa[2][2];
#pragma unroll
    for (int s = 0; s < 2; ++s)
#pragma unroll
        for (int h = 0; h < 2; ++h) {
            size_t off = (size_t)(b * SEQ + qbase + s*16 + l16) * D_MODEL
                       + head * HEAD_DIM + h*32 + quad*8;
            qa[s][h] = *(const bf16x8*)(Qb + off);
        }

    f32x4 acc[2][4];     // [strip][d-tile], C-layout row=q, col=d
    f32x4 acc_sum[2];    // row sums via MFMA(P, ones): denom(q) broadcast to all cols
#pragma unroll
    for (int s = 0; s < 2; ++s) {
#pragma unroll
        for (int dt = 0; dt < 4; ++dt) acc[s][dt] = (f32x4){0.f,0.f,0.f,0.f};
        acc_sum[s] = (f32x4){0.f,0.f,0.f,0.f};
    }

    // all-ones bf16 B-operand (1.0bf16 = 0x3F80)
    bf16x8 vones;
#pragma unroll
    for (int i = 0; i < 8; ++i) vones[i] = (short)0x3F80;

    const size_t kbase  = (size_t)(b * SEQ) * D_MODEL + head * HEAD_DIM;
    const size_t vtbase = (size_t)((b * NUM_HEADS + head) * HEAD_DIM) * SEQ;

    // prologue: stage k-block 0 into buffer 0
#pragma unroll
    for (int j = 0; j < 2; ++j) {
        const int seg = j * 4 + w;
        const int i = seg * 64 + lane;
        const int r = i >> 3;
        const int ck = (i & 7) ^ ((r & 3) | ((r >> 1) & 4));
        const int cv = (i & 7) ^ (r & 7);
        gld_lds16(Kb + kbase + (size_t)r * D_MODEL + ck * 8, &Ks[0][seg * 512]);
        gld_lds16(Vt + vtbase + (size_t)r * SEQ + cv * 8, &Vs[0][seg * 512]);
    }

    int ib = 0;
    for (int kb = 0; kb < SEQ; kb += 64, ib ^= 1) {
        __syncthreads();   // buf ib staged

        if (kb + 64 < SEQ) {
#pragma unroll
            for (int j = 0; j < 2; ++j) {
                const int seg = j * 4 + w;
                const int i = seg * 64 + lane;
                const int r = i >> 3;
                const int ck = (i & 7) ^ ((r & 3) | ((r >> 1) & 4));
                const int cv = (i & 7) ^ (r & 7);
                gld_lds16(Kb + kbase + (size_t)(kb + 64 + r) * D_MODEL + ck * 8,
                          &Ks[ib ^ 1][seg * 512]);
                gld_lds16(Vt + vtbase + (size_t)r * SEQ + kb + 64 + cv * 8,
                          &Vs[ib ^ 1][seg * 512]);
            }
        }

        // K fragments, permuted rows (A-row a holds key kh*32+(a>>2)*8+m*4+(a&3))
        bf16x8 kf[2][2][2];   // [kh][m][h]
#pragma unroll
        for (int kh = 0; kh < 2; ++kh)
#pragma unroll
            for (int m = 0; m < 2; ++m) {
                const int r = kh * 32 + ((l16 >> 2) << 3) + m * 4 + (l16 & 3);
                const int sg = (r & 3) | ((r >> 1) & 4);
#pragma unroll
                for (int h = 0; h < 2; ++h) {
                    const int cc = (h * 4 + quad) ^ sg;
                    kf[kh][m][h] = *(const bf16x8*)&Ks[ib][(r * 8 + cc) * 8];
                }
            }

#pragma unroll
        for (int kh = 0; kh < 2; ++kh) {
            // S^T = K Q^T with interleaved key rows; exp2; pack -> in-reg pf
            bf16x8 pf[2];
#pragma unroll
            for (int s = 0; s < 2; ++s) {
                f32x4 st0 = (f32x4){0.f,0.f,0.f,0.f};
                f32x4 st1 = (f32x4){0.f,0.f,0.f,0.f};
#pragma unroll
                for (int h = 0; h < 2; ++h) {
                    st0 = __builtin_amdgcn_mfma_f32_16x16x32_bf16(
                        kf[kh][0][h], qa[s][h], st0, 0, 0, 0);
                    st1 = __builtin_amdgcn_mfma_f32_16x16x32_bf16(
                        kf[kh][1][h], qa[s][h], st1, 0, 0, 0);
                }
                // lane holds keys kh*32 + quad*8 + {0..7} for q = s*16+l16
                float p0 = __builtin_amdgcn_exp2f(st0[0]);
                float p1 = __builtin_amdgcn_exp2f(st0[1]);
                float p2 = __builtin_amdgcn_exp2f(st0[2]);
                float p3 = __builtin_amdgcn_exp2f(st0[3]);
                float p4 = __builtin_amdgcn_exp2f(st1[0]);
                float p5 = __builtin_amdgcn_exp2f(st1[1]);
                float p6 = __builtin_amdgcn_exp2f(st1[2]);
                float p7 = __builtin_amdgcn_exp2f(st1[3]);
                __hip_bfloat162 w0 = __float22bfloat162_rn(make_float2(p0, p1));
                __hip_bfloat162 w1 = __float22bfloat162_rn(make_float2(p2, p3));
                __hip_bfloat162 w2 = __float22bfloat162_rn(make_float2(p4, p5));
                __hip_bfloat162 w3 = __float22bfloat162_rn(make_float2(p6, p7));
                union { bf16x8 v; unsigned int u[4]; } pu;
                pu.u[0] = *reinterpret_cast<unsigned int*>(&w0);
                pu.u[1] = *reinterpret_cast<unsigned int*>(&w1);
                pu.u[2] = *reinterpret_cast<unsigned int*>(&w2);
                pu.u[3] = *reinterpret_cast<unsigned int*>(&w3);
                pf[s] = pu.v;
            }

            // O += P V (pf in-register, vf from LDS); row-sum via MFMA(P, 1)
#pragma unroll
            for (int dt = 0; dt < 4; ++dt) {
                const int r = dt * 16 + l16;
                const int cv = (kh * 4 + quad) ^ (r & 7);
                bf16x8 vf = *(const bf16x8*)&Vs[ib][(r * 8 + cv) * 8];
#pragma unroll
                for (int s = 0; s < 2; ++s)
                    acc[s][dt] = __builtin_amdgcn_mfma_f32_16x16x32_bf16(
                        pf[s], vf, acc[s][dt], 0, 0, 0);
            }
#pragma unroll
            for (int s = 0; s < 2; ++s)
                acc_sum[s] = __builtin_amdgcn_mfma_f32_16x16x32_bf16(
                    pf[s], vones, acc_sum[s], 0, 0, 0);
        }
    }

    // epilogue: denom(q = s*16+quad*4+rr) is in acc_sum[s][rr] of every lane
#pragma unroll
    for (int s = 0; s < 2; ++s)
#pragma unroll
        for (int rr = 0; rr < 4; ++rr) {
            float inv = 1.0f / acc_sum[s][rr];
            int q = qbase + s*16 + quad*4 + rr;
            unsigned short* orow = O + (size_t)(b * SEQ + q) * D_MODEL + head * HEAD_DIM + l16;
#pragma unroll
            for (int dt = 0; dt < 4; ++dt) orow[dt*16] = f2bf(acc[s][dt][rr] * inv);
        }
}

extern "C" void kernel_launch(void* const* d_in, const int* in_sizes, int n_in,
                              void* d_out, int out_size, void* d_ws, size_t ws_size,
                              hipStream_t stream) {
    const float* x    = (const float*)d_in[0];
    const float* wq_c = (const float*)d_in[1];
    const float* wq_b = (const float*)d_in[2];
    const float* wk_c = (const float*)d_in[3];
    const float* wk_b = (const float*)d_in[4];
    const float* wv_c = (const float*)d_in[5];
    const float* wv_b = (const float*)d_in[6];
    const float* wo_c = (const float*)d_in[7];
    const float* wo_b = (const float*)d_in[8];
    float* out = (float*)d_out;

    char* ws = (char*)d_ws;
    unsigned short* Wt   = (unsigned short*)(ws);                        // 8 MB
    float*          bias = (float*)(ws + ((size_t)8  << 20));            // 16 KB
    unsigned short* xb   = (unsigned short*)(ws + ((size_t)10 << 20));   // 16 MB
    unsigned short* Qb   = (unsigned short*)(ws + ((size_t)26 << 20));   // 16 MB
    unsigned short* Kb   = (unsigned short*)(ws + ((size_t)42 << 20));   // 16 MB
    unsigned short* Vt   = (unsigned short*)(ws + ((size_t)58 << 20));   // 16 MB
    unsigned short* Ob   = (unsigned short*)(ws + ((size_t)74 << 20));   // 16 MB

    build_w<<<4096, 256, 0, stream>>>(wq_c, wk_c, wv_c, wo_c,
                                      wq_b, wk_b, wv_b, wo_b, Wt, bias);
    xcast<<<MROWS, 256, 0, stream>>>(x, xb);
    gemm_circ<0><<<dim3(64, 24), 256, 0, stream>>>(xb, Wt, bias, Qb, Kb, Vt, nullptr);
    // fast axis = (b,head): round-robin over XCDs; q-tiles (slow) revisit warm L2
    attn_mfma<<<dim3(BATCH * NUM_HEADS, SEQ / 128), 256, 0, stream>>>(Qb, Kb, Vt, Ob);
    gemm_circ<1><<<dim3(64, 8), 256, 0, stream>>>(Ob, Wt + (size_t)3072 * 1024,
                                                  bias + 3072, nullptr, nullptr, nullptr, out);
}